// Round 6
// baseline (297.082 us; speedup 1.0000x reference)
//
#include <hip/hip_runtime.h>

#define HW   4096
#define CHW  262144
#define NPQ  441
#define KPAD 448
#define CSTR 456   // k_main/k_main2 LDS cor row stride (shorts)
#define CSTA 460   // k_cor LDS tile row stride (shorts)

typedef __attribute__((ext_vector_type(8))) short bf16x8;
typedef __attribute__((ext_vector_type(4))) float f32x4;

#define MFMA16(a,b,c) __builtin_amdgcn_mfma_f32_16x16x32_bf16(a,b,c,0,0,0)

__device__ __forceinline__ short f2bf(float f){
  unsigned u = __float_as_uint(f);
  return (short)((u + 0x7FFFu + ((u >> 16) & 1u)) >> 16);
}
__device__ __forceinline__ float bf2f(short s){
  return __uint_as_float(((unsigned)(unsigned short)s) << 16);
}

// Fragment load from transposed bf16 tensor X[plane][row][w][c] (c innermost).
__device__ __forceinline__ bf16x8 load_fragX(const short* rowX, int pi, int tile,
                                             int kk, int lane){
  const int m = lane & 15, kg = lane >> 4;
  return *(const bf16x8*)(rowX + (2*(tile*16 + m) + pi)*64 + kk*32 + kg*8);
}

// ---------------- Pass 0: fp32 [pl][c][h][w] -> bf16 X[pl-plane0][h][w][c] ----------------
__global__ __launch_bounds__(256,4) void k_transpose(const float* __restrict__ feats,
                                                     short* __restrict__ X, int plane0)
{
  __shared__ float tile[64*65];
  const int tid = threadIdx.x;
  const int pll = blockIdx.x >> 6, h = blockIdx.x & 63;
  const float* pb = feats + (size_t)(plane0 + pll)*CHW + h*64;
#pragma unroll
  for (int k = 0; k < 4; ++k){
    const int idx = tid + k*256;
    const int c = idx >> 4, w4 = idx & 15;
    f32x4 v = *(const f32x4*)(pb + c*HW + w4*4);
#pragma unroll
    for (int j = 0; j < 4; ++j) tile[c*65 + w4*4 + j] = v[j];
  }
  __syncthreads();
  short* xb = X + ((size_t)pll*64 + h)*4096;
#pragma unroll
  for (int s = 0; s < 2; ++s){
    const int chunk = tid + s*256;
    const int w = chunk >> 3, cg = chunk & 7;
    bf16x8 r;
#pragma unroll
    for (int j = 0; j < 8; ++j) r[j] = f2bf(tile[(cg*8 + j)*65 + w]);
    *(bf16x8*)(xb + w*64 + cg*8) = r;
  }
}

// ======================= NEW PATH =======================
// k_cor: block=(n,h,pi). Gram (prefetched) -> reg-scatter band into 32x460 LDS tile,
// then column sums (BN stats partials) + tile -> global cor buffer [n][h][pi][i][448].
__global__ __launch_bounds__(256,4) void k_cor(const short* __restrict__ X,
    short* __restrict__ corg, float* __restrict__ gpartS, float* __restrict__ gpartQ)
{
  __shared__ __align__(16) short tile[32*CSTA];
  const int tid = threadIdx.x, wv = tid >> 6, lane = tid & 63;
  const int bi = blockIdx.x;
  const int pi = bi & 1, h = (bi >> 1) & 63, nn = bi >> 7;
  const int pl1 = (nn/7)*8 + (nn%7);
  const short* f1r  = X + ((size_t)pl1*64 + h)*4096;
  const short* f2pl = X + (size_t)(pl1 + 1)*64*4096;

  {
    int4 z = {0,0,0,0};
    for (int idx = tid; idx < 32*CSTA/8; idx += 256) ((int4*)tile)[idx] = z;
  }

  // A fragments: one parity per block -> load once
  bf16x8 afr[2][2];
#pragma unroll
  for (int mt = 0; mt < 2; ++mt)
#pragma unroll
    for (int kk = 0; kk < 2; ++kk)
      afr[mt][kk] = load_fragX(f1r, pi, mt, kk, lane);

  __syncthreads();   // tile zeroed before any scatter

  const int cI = (lane >> 4)*4;   // C-layout: row=(lane>>4)*4+reg, col=lane&15
  const int cJ = lane & 15;

  // software-pipelined B loads: u = it*4 + wv, p = u (0..20)
  auto clampr = [&](int r){ return r < 0 ? 0 : (r > 63 ? 63 : r); };
  bf16x8 b[4], nb[4];
  {
    const int row0 = clampr(h + 2*wv - 20);
    const short* f2r = f2pl + row0*4096;
    b[0] = load_fragX(f2r, pi, 0, 0, lane);
    b[1] = load_fragX(f2r, pi, 1, 0, lane);
    b[2] = load_fragX(f2r, pi, 0, 1, lane);
    b[3] = load_fragX(f2r, pi, 1, 1, lane);
  }
  for (int it = 0; it < 6; ++it){
    const int u = it*4 + wv;
    const int row = h + 2*u - 20;
    if (it < 5){
      const int rown = clampr(row + 8);
      const short* f2r = f2pl + rown*4096;
      nb[0] = load_fragX(f2r, pi, 0, 0, lane);
      nb[1] = load_fragX(f2r, pi, 1, 0, lane);
      nb[2] = load_fragX(f2r, pi, 0, 1, lane);
      nb[3] = load_fragX(f2r, pi, 1, 1, lane);
    }
    if (u < 21 && (unsigned)row < 64u){
      f32x4 a00 = {0.f,0.f,0.f,0.f}, a01 = a00, a10 = a00, a11 = a00;
      a00 = MFMA16(afr[0][0], b[0], a00);
      a01 = MFMA16(afr[0][0], b[1], a01);
      a10 = MFMA16(afr[1][0], b[0], a10);
      a11 = MFMA16(afr[1][0], b[1], a11);
      a00 = MFMA16(afr[0][1], b[2], a00);
      a01 = MFMA16(afr[0][1], b[3], a01);
      a10 = MFMA16(afr[1][1], b[2], a10);
      a11 = MFMA16(afr[1][1], b[3], a11);
      const int p21 = u*21;
      // G[i][j] -> tile[i][p*21 + (j-i+10)]
#define SCAT(v, ii, jj) do{ int q_ = (jj) - (ii) + 10; \
        if ((unsigned)q_ < 21u) tile[(ii)*CSTA + p21 + q_] = f2bf(v); }while(0)
#pragma unroll
      for (int r = 0; r < 4; ++r){
        const int i0 = cI + r;
        SCAT(a00[r], i0,      cJ);
        SCAT(a01[r], i0,      cJ + 16);
        SCAT(a10[r], i0 + 16, cJ);
        SCAT(a11[r], i0 + 16, cJ + 16);
      }
#undef SCAT
    }
#pragma unroll
    for (int j = 0; j < 4; ++j) b[j] = nb[j];
  }
  __syncthreads();

  // BN stats partials: column sums over 32 rows, 56 groups of 8 cols
  {
    const int g = tid >> 2, sub = tid & 3;
    if (g < 56){
      float s[8], s2[8];
#pragma unroll
      for (int j = 0; j < 8; ++j){ s[j] = 0.f; s2[j] = 0.f; }
      for (int rr = 0; rr < 8; ++rr){
        const int row = sub*8 + rr;
        bf16x8 v = *(const bf16x8*)&tile[row*CSTA + g*8];
#pragma unroll
        for (int j = 0; j < 8; ++j){
          float f = bf2f(v[j]);
          s[j] += f; s2[j] += f*f;
        }
      }
#pragma unroll
      for (int j = 0; j < 8; ++j){
        s[j]  += __shfl_xor(s[j], 1);  s[j]  += __shfl_xor(s[j], 2);
        s2[j] += __shfl_xor(s2[j], 1); s2[j] += __shfl_xor(s2[j], 2);
      }
      if (sub == 0){
        const int slot = (bi & 31)*KPAD + g*8;
#pragma unroll
        for (int j = 0; j < 8; ++j){
          atomicAdd(&gpartS[slot + j], s[j]);
          atomicAdd(&gpartQ[slot + j], s2[j]);
        }
      }
    }
  }

  // tile -> global: 32 rows x 56 b128 chunks (448 shorts/row = 56 chunks, NOT 28)
  short* cblk = corg + (size_t)bi*14336;   // 32*448
  for (int c = tid; c < 1792; c += 256){
    const int row = c/56, cg = c - row*56;
    *(bf16x8*)(cblk + row*KPAD + cg*8) = *(const bf16x8*)&tile[row*CSTA + cg*8];
  }
}

// k_finalizeB: fold 32 stat slots -> BN scale/shift -> wpT (bf16) + bias
__global__ __launch_bounds__(256) void k_finalizeB(const float* __restrict__ gpartS,
    const float* __restrict__ gpartQ, const float* __restrict__ gamma,
    const float* __restrict__ beta, const float* __restrict__ convw,
    short* __restrict__ wpT, float* __restrict__ bias)
{
  __shared__ float s_scale[NPQ], s_shift[NPQ];
  const int tid = threadIdx.x;
  for (int k = tid; k < NPQ; k += 256){
    float s = 0.f, q = 0.f;
    for (int sl = 0; sl < 32; ++sl){
      s += gpartS[sl*KPAD + k];
      q += gpartQ[sl*KPAD + k];
    }
    float m  = s * (1.f/114688.f);
    float v  = q * (1.f/114688.f) - m*m;
    float iv = rsqrtf(v + 1e-5f);
    float sc = gamma[k] * iv;
    s_scale[k] = sc;
    s_shift[k] = beta[k] - m*sc;
  }
  __syncthreads();
  for (int idx = tid; idx < 64*KPAD; idx += 256){
    int o = idx / KPAD, k = idx - o*KPAD;
    float w = (k < NPQ) ? convw[o*NPQ + k] * s_scale[k] : 0.f;
    wpT[idx] = f2bf(w);
  }
  if (tid < 64){
    float b = 0.f;
    for (int k = 0; k < NPQ; ++k) b += s_shift[k] * convw[tid*NPQ + k];
    bias[tid] = b;
  }
}

// k_main2: stage cor tile from global (pixel-reordered), GEMM2, coalesced epilogue
__global__ __launch_bounds__(256,2) void k_main2(const short* __restrict__ corg,
    const short* __restrict__ wpT, const float* __restrict__ bias,
    float* __restrict__ out)
{
  __shared__ __align__(16) short cor[64*CSTR];
  const int tid = threadIdx.x, wv = tid >> 6, lane = tid & 63;
  const int nn = blockIdx.x >> 6, h = blockIdx.x & 63;
  const int pl1g = (nn/7)*8 + (nn%7);
  const short* cblk = corg + (size_t)(nn*64 + h)*28672;   // [pi][i][448]

  // stage 64x448 shorts = 3584 b128 chunks; reorder rows rho=pi*32+i -> pixel w=2i+pi
#pragma unroll
  for (int s = 0; s < 14; ++s){
    const int c = tid + s*256;              // 3584 chunks (56 per row, NOT 28)
    const int rho = c/56, cg = c - rho*56;
    const int w = ((rho & 31) << 1) | (rho >> 5);
    bf16x8 v = *(const bf16x8*)(cblk + c*8);
    *(bf16x8*)&cor[w*CSTR + cg*8] = v;
  }
  __syncthreads();

  // GEMM2: D[o][pix] = sum_k wpT[o][k] * cor[pix][k]
  const int m = lane & 15, kg = lane >> 4;
  const short* wrow = wpT + (wv*16 + m)*KPAD;
  f32x4 acc[4];
#pragma unroll
  for (int nt = 0; nt < 4; ++nt) acc[nt] = (f32x4){0.f,0.f,0.f,0.f};
  for (int kk = 0; kk < 14; ++kk){
    const int k0 = kk*32 + kg*8;
    bf16x8 aw = *(const bf16x8*)(wrow + k0);
#pragma unroll
    for (int nt = 0; nt < 4; ++nt){
      bf16x8 bc = *(const bf16x8*)&cor[(nt*16 + m)*CSTR + k0];
      acc[nt] = MFMA16(aw, bc, acc[nt]);
    }
  }
  const int r0 = (lane >> 4)*4;
  float bo[4];
#pragma unroll
  for (int r = 0; r < 4; ++r) bo[r] = bias[wv*16 + r0 + r];
  float* outb = out + (size_t)pl1g*CHW + h*64;
#pragma unroll
  for (int nt = 0; nt < 4; ++nt)
#pragma unroll
    for (int r = 0; r < 4; ++r){
      const int o = wv*16 + r0 + r;
      outb[o*HW + nt*16 + m] = acc[nt][r] + bo[r];
    }
}

// ======================= FALLBACK PATH (R4, verified) =======================
__global__ __launch_bounds__(256,2) void k_stats(const short* __restrict__ X,
                                                 float* __restrict__ gsum,
                                                 float* __restrict__ gssq,
                                                 int n0, int plane0)
{
  __shared__ float Gbuf[4*1056];
  __shared__ float s_sum[2][NPQ];
  __shared__ float s_ssq[2][NPQ];
  const int tid = threadIdx.x, wv = tid >> 6, lane = tid & 63;
  const int nn = n0 + (blockIdx.x >> 6), h = blockIdx.x & 63;
  const int pl1 = (nn/7)*8 + (nn%7) - plane0;
  const short* f1r  = X + ((size_t)pl1*64 + h)*4096;
  const short* f2pl = X + (size_t)(pl1 + 1)*64*4096;
  float* Gw = Gbuf + wv*1056;

  for (int i = tid; i < 2*NPQ; i += 256){
    (&s_sum[0][0])[i] = 0.f; (&s_ssq[0][0])[i] = 0.f;
  }
  __syncthreads();

  bf16x8 afr[2][2];
  int cur_pi = -1;
  for (int it = 0; it < 11; ++it){
    const int u = it*4 + wv;
    const bool active = (u < 42);
    const int pi = (u >= 21) ? 1 : 0;
    const int p  = u - pi*21;
    const int row = h + 2*p - 20;
    const bool rv = active && ((unsigned)row < 64u);

    if (active && pi != cur_pi){
#pragma unroll
      for (int mt = 0; mt < 2; ++mt)
#pragma unroll
        for (int kk = 0; kk < 2; ++kk)
          afr[mt][kk] = load_fragX(f1r, pi, mt, kk, lane);
      cur_pi = pi;
    }

    if (rv){
      const short* f2r = f2pl + row*4096;
      f32x4 a00 = {0.f,0.f,0.f,0.f}, a01 = a00, a10 = a00, a11 = a00;
#pragma unroll
      for (int kk = 0; kk < 2; ++kk){
        bf16x8 b0 = load_fragX(f2r, pi, 0, kk, lane);
        bf16x8 b1 = load_fragX(f2r, pi, 1, kk, lane);
        a00 = MFMA16(afr[0][kk], b0, a00);
        a01 = MFMA16(afr[0][kk], b1, a01);
        a10 = MFMA16(afr[1][kk], b0, a10);
        a11 = MFMA16(afr[1][kk], b1, a11);
      }
      const int cI = (lane >> 4)*4;
      const int cJ = lane & 15;
#pragma unroll
      for (int r = 0; r < 4; ++r){
        Gw[(cJ     )*33 + cI + r     ] = a00[r];
        Gw[(cJ + 16)*33 + cI + r     ] = a01[r];
        Gw[(cJ     )*33 + cI + r + 16] = a10[r];
        Gw[(cJ + 16)*33 + cI + r + 16] = a11[r];
      }
    }
    __syncthreads();

    if (rv){
      const int q = lane / 3;
      const int seg = lane - q*3;
      float s = 0.f, s2 = 0.f;
      if (lane < 63){
        const int i0 = seg*11;
        const int i1 = (seg == 2) ? 32 : i0 + 11;
        for (int i = i0; i < i1; ++i){
          const int j = i + q - 10;
          if ((unsigned)j < 32u){
            float v = Gw[j*33 + i];
            s += v; s2 += v*v;
          }
        }
      }
      float sA = __shfl(s,  lane+1), sB = __shfl(s,  lane+2);
      float tA = __shfl(s2, lane+1), tB = __shfl(s2, lane+2);
      if (lane < 63 && seg == 0){
        s_sum[pi][p*21 + q] += s + sA + sB;
        s_ssq[pi][p*21 + q] += s2 + tA + tB;
      }
    }
  }
  __syncthreads();

  for (int i = tid; i < NPQ; i += 256){
    atomicAdd(&gsum[i], s_sum[0][i] + s_sum[1][i]);
    atomicAdd(&gssq[i], s_ssq[0][i] + s_ssq[1][i]);
  }
}

__global__ __launch_bounds__(256) void k_finalizeA(const float* __restrict__ gsum,
    const float* __restrict__ gssq, const float* __restrict__ gamma,
    const float* __restrict__ beta, const float* __restrict__ convw,
    short* __restrict__ wpT, float* __restrict__ bias)
{
  __shared__ float s_scale[NPQ], s_shift[NPQ];
  const int tid = threadIdx.x;
  for (int k = tid; k < NPQ; k += 256){
    float m  = gsum[k] * (1.f/114688.f);
    float v  = gssq[k] * (1.f/114688.f) - m*m;
    float iv = rsqrtf(v + 1e-5f);
    float sc = gamma[k] * iv;
    s_scale[k] = sc;
    s_shift[k] = beta[k] - m*sc;
  }
  __syncthreads();
  for (int idx = tid; idx < 64*KPAD; idx += 256){
    int o = idx / KPAD, k = idx - o*KPAD;
    float w = (k < NPQ) ? convw[o*NPQ + k] * s_scale[k] : 0.f;
    wpT[idx] = f2bf(w);
  }
  if (tid < 64){
    float b = 0.f;
    for (int k = 0; k < NPQ; ++k) b += s_shift[k] * convw[tid*NPQ + k];
    bias[tid] = b;
  }
}

__global__ __launch_bounds__(256,2) void k_main(const short* __restrict__ X,
    const short* __restrict__ wpT, const float* __restrict__ bias,
    float* __restrict__ out, int n0, int plane0)
{
  __shared__ __align__(16) short cor[64*CSTR];
  const int tid = threadIdx.x, wv = tid >> 6, lane = tid & 63;
  const int nn = n0 + (blockIdx.x >> 6), h = blockIdx.x & 63;
  const int pl1g = (nn/7)*8 + (nn%7);
  const int pl1 = pl1g - plane0;
  const short* f1r  = X + ((size_t)pl1*64 + h)*4096;
  const short* f2pl = X + (size_t)(pl1 + 1)*64*4096;

  {
    int4 z = {0,0,0,0};
    for (int idx = tid; idx < 64*CSTR/8; idx += 256) ((int4*)cor)[idx] = z;
  }
  __syncthreads();

  bf16x8 afr[2][2];
  int cur_pi = -1;
  for (int it = 0; it < 11; ++it){
    const int u = it*4 + wv;
    const bool active = (u < 42);
    const int pi = (u >= 21) ? 1 : 0;
    const int p  = u - pi*21;
    const int row = h + 2*p - 20;
    const bool rv = active && ((unsigned)row < 64u);

    if (active && pi != cur_pi){
#pragma unroll
      for (int mt = 0; mt < 2; ++mt)
#pragma unroll
        for (int kk = 0; kk < 2; ++kk)
          afr[mt][kk] = load_fragX(f1r, pi, mt, kk, lane);
      cur_pi = pi;
    }

    if (rv){
      const short* f2r = f2pl + row*4096;
      f32x4 a00 = {0.f,0.f,0.f,0.f}, a01 = a00, a10 = a00, a11 = a00;
#pragma unroll
      for (int kk = 0; kk < 2; ++kk){
        bf16x8 b0 = load_fragX(f2r, pi, 0, kk, lane);
        bf16x8 b1 = load_fragX(f2r, pi, 1, kk, lane);
        a00 = MFMA16(afr[0][kk], b0, a00);
        a01 = MFMA16(afr[0][kk], b1, a01);
        a10 = MFMA16(afr[1][kk], b0, a10);
        a11 = MFMA16(afr[1][kk], b1, a11);
      }
      const int cI = (lane >> 4)*4;
      const int cJ = lane & 15;
      const int p21 = p*21;
#define SCAT(v, ii, jj) do{ int q_ = (jj) - (ii) + 10; \
        if ((unsigned)q_ < 21u) cor[(2*(ii)+pi)*CSTR + p21 + q_] = f2bf(v); }while(0)
#pragma unroll
      for (int r = 0; r < 4; ++r){
        const int i0 = cI + r;
        SCAT(a00[r], i0,      cJ);
        SCAT(a01[r], i0,      cJ + 16);
        SCAT(a10[r], i0 + 16, cJ);
        SCAT(a11[r], i0 + 16, cJ + 16);
      }
#undef SCAT
    }
  }
  __syncthreads();

  const int m = lane & 15, kg = lane >> 4;
  const short* wrow = wpT + (wv*16 + m)*KPAD;
  f32x4 acc[4];
#pragma unroll
  for (int nt = 0; nt < 4; ++nt) acc[nt] = (f32x4){0.f,0.f,0.f,0.f};
  for (int kk = 0; kk < 14; ++kk){
    const int k0 = kk*32 + kg*8;
    bf16x8 aw = *(const bf16x8*)(wrow + k0);
#pragma unroll
    for (int nt = 0; nt < 4; ++nt){
      bf16x8 bc = *(const bf16x8*)&cor[(nt*16 + m)*CSTR + k0];
      acc[nt] = MFMA16(aw, bc, acc[nt]);
    }
  }
  const int r0 = (lane >> 4)*4;
  float bo[4];
#pragma unroll
  for (int r = 0; r < 4; ++r) bo[r] = bias[wv*16 + r0 + r];
  float* outb = out + (size_t)pl1g*CHW + h*64;
#pragma unroll
  for (int nt = 0; nt < 4; ++nt)
#pragma unroll
    for (int r = 0; r < 4; ++r){
      const int o = wv*16 + r0 + r;
      outb[o*HW + nt*16 + m] = acc[nt][r] + bo[r];
    }
}

// ---------------- zero frame T=7 ----------------
__global__ __launch_bounds__(256) void k_zero(float* __restrict__ out){
  const int idx = blockIdx.x*256 + threadIdx.x;
  const int b = idx >> 16, r = idx & 65535;
  float4* p = (float4*)(out + (size_t)(b*8 + 7)*CHW);
  p[r] = make_float4(0.f, 0.f, 0.f, 0.f);
}

extern "C" void kernel_launch(void* const* d_in, const int* in_sizes, int n_in,
                              void* d_out, int out_size, void* d_ws, size_t ws_size,
                              hipStream_t stream)
{
  const float* feats = (const float*)d_in[0];
  const float* gamma = (const float*)d_in[1];
  const float* beta  = (const float*)d_in[2];
  const float* convw = (const float*)d_in[3];
  float* out = (float*)d_out;
  float* wsf = (float*)d_ws;

  // ---- new-path workspace layout (floats) ----
  float* gpartS = wsf;                       // [0, 14336)           32*448
  float* gpartQ = wsf + 14336;               // [14336, 28672)
  float* biasB  = wsf + 28672;               // [28672, 28736)
  short* wpTB   = (short*)(wsf + 28736);     // 64*448 shorts -> [28736, 43072)
  short* Xn     = (short*)(wsf + 43072);     // 16.78 MB -> ends 4237376 floats
  short* corg   = (short*)(wsf + 4237376);   // 3584*14336 shorts = 102.8 MB
  const size_t need_new = (size_t)4237376*4 + (size_t)3584*14336*2;

  k_zero<<<1024, 256, 0, stream>>>(out);

  if (ws_size >= need_new){
    hipMemsetAsync(gpartS, 0, 2*14336*sizeof(float), stream);
    k_transpose<<<2048, 256, 0, stream>>>(feats, Xn, 0);
    k_cor<<<3584, 256, 0, stream>>>(Xn, corg, gpartS, gpartQ);
    k_finalizeB<<<1, 256, 0, stream>>>(gpartS, gpartQ, gamma, beta, convw, wpTB, biasB);
    k_main2<<<1792, 256, 0, stream>>>(corg, wpTB, biasB, out);
    return;
  }

  // ---- fallback (R4 verified) ----
  float* gsum = wsf;
  float* gssq = wsf + 441;
  float* bias = wsf + 896;
  short* wpT  = (short*)(wsf + 1024);
  short* X    = (short*)(wsf + 16384);
  const size_t fixedB = 16384*sizeof(float);
  const size_t planeB = (size_t)CHW*2;

  hipMemsetAsync(gsum, 0, 882*sizeof(float), stream);
  if (ws_size >= fixedB + 32*planeB){
    k_transpose<<<2048, 256, 0, stream>>>(feats, X, 0);
    k_stats<<<1792, 256, 0, stream>>>(X, gsum, gssq, 0, 0);
    k_finalizeA<<<1, 256, 0, stream>>>(gsum, gssq, gamma, beta, convw, wpT, bias);
    k_main<<<1792, 256, 0, stream>>>(X, wpT, bias, out, 0, 0);
  } else if (ws_size >= fixedB + 8*planeB){
    for (int b = 0; b < 4; ++b){
      k_transpose<<<512, 256, 0, stream>>>(feats, X, b*8);
      k_stats<<<448, 256, 0, stream>>>(X, gsum, gssq, b*7, b*8);
    }
    k_finalizeA<<<1, 256, 0, stream>>>(gsum, gssq, gamma, beta, convw, wpT, bias);
    for (int b = 0; b < 4; ++b){
      k_transpose<<<512, 256, 0, stream>>>(feats, X, b*8);
      k_main<<<448, 256, 0, stream>>>(X, wpT, bias, out, b*7, b*8);
    }
  } else {
    for (int n = 0; n < 28; ++n){
      const int pl = (n/7)*8 + (n%7);
      k_transpose<<<128, 256, 0, stream>>>(feats, X, pl);
      k_stats<<<64, 256, 0, stream>>>(X, gsum, gssq, n, pl);
    }
    k_finalizeA<<<1, 256, 0, stream>>>(gsum, gssq, gamma, beta, convw, wpT, bias);
    for (int n = 0; n < 28; ++n){
      const int pl = (n/7)*8 + (n%7);
      k_transpose<<<128, 256, 0, stream>>>(feats, X, pl);
      k_main<<<64, 256, 0, stream>>>(X, wpT, bias, out, n, pl);
    }
  }
}

// Round 7
// 249.031 us; speedup vs baseline: 1.1930x; 1.1930x over previous
//
#include <hip/hip_runtime.h>

#define HW   4096
#define CHW  262144
#define NPQ  441
#define KPAD 448
#define CSTR 456   // k_main/k_main2 LDS cor row stride (shorts)
#define CSTA 460   // k_cor LDS tile row stride (shorts)

typedef __attribute__((ext_vector_type(8))) short bf16x8;
typedef __attribute__((ext_vector_type(4))) float f32x4;

#define MFMA16(a,b,c) __builtin_amdgcn_mfma_f32_16x16x32_bf16(a,b,c,0,0,0)

__device__ __forceinline__ short f2bf(float f){
  unsigned u = __float_as_uint(f);
  return (short)((u + 0x7FFFu + ((u >> 16) & 1u)) >> 16);
}
__device__ __forceinline__ float bf2f(short s){
  return __uint_as_float(((unsigned)(unsigned short)s) << 16);
}

__device__ __forceinline__ bf16x8 load_fragX(const short* rowX, int pi, int tile,
                                             int kk, int lane){
  const int m = lane & 15, kg = lane >> 4;
  return *(const bf16x8*)(rowX + (2*(tile*16 + m) + pi)*64 + kk*32 + kg*8);
}

// ---------------- Pass 0: fp32 [pl][c][h][w] -> bf16 X[pl-plane0][h][w][c] ----------------
__global__ __launch_bounds__(256,4) void k_transpose(const float* __restrict__ feats,
                                                     short* __restrict__ X, int plane0)
{
  __shared__ float tile[64*65];
  const int tid = threadIdx.x;
  const int pll = blockIdx.x >> 6, h = blockIdx.x & 63;
  const float* pb = feats + (size_t)(plane0 + pll)*CHW + h*64;
#pragma unroll
  for (int k = 0; k < 4; ++k){
    const int idx = tid + k*256;
    const int c = idx >> 4, w4 = idx & 15;
    f32x4 v = *(const f32x4*)(pb + c*HW + w4*4);
#pragma unroll
    for (int j = 0; j < 4; ++j) tile[c*65 + w4*4 + j] = v[j];
  }
  __syncthreads();
  short* xb = X + ((size_t)pll*64 + h)*4096;
#pragma unroll
  for (int s = 0; s < 2; ++s){
    const int chunk = tid + s*256;
    const int w = chunk >> 3, cg = chunk & 7;
    bf16x8 r;
#pragma unroll
    for (int j = 0; j < 8; ++j) r[j] = f2bf(tile[(cg*8 + j)*65 + w]);
    *(bf16x8*)(xb + w*64 + cg*8) = r;
  }
}

// ======================= PREFERRED PATH (no global atomics) =======================
// k_cor2: Gram -> band tile -> column-sum partials (PLAIN stores) + corg writeback.
__global__ __launch_bounds__(256,4) void k_cor2(const short* __restrict__ X,
    short* __restrict__ corg, float* __restrict__ partS, float* __restrict__ partQ)
{
  __shared__ __align__(16) short tile[32*CSTA];
  const int tid = threadIdx.x, wv = tid >> 6, lane = tid & 63;
  const int bi = blockIdx.x;
  const int pi = bi & 1, h = (bi >> 1) & 63, nn = bi >> 7;
  const int pl1 = (nn/7)*8 + (nn%7);
  const short* f1r  = X + ((size_t)pl1*64 + h)*4096;
  const short* f2pl = X + (size_t)(pl1 + 1)*64*4096;

  {
    int4 z = {0,0,0,0};
    for (int idx = tid; idx < 32*CSTA/8; idx += 256) ((int4*)tile)[idx] = z;
  }

  bf16x8 afr[2][2];
#pragma unroll
  for (int mt = 0; mt < 2; ++mt)
#pragma unroll
    for (int kk = 0; kk < 2; ++kk)
      afr[mt][kk] = load_fragX(f1r, pi, mt, kk, lane);

  __syncthreads();

  const int cI = (lane >> 4)*4;
  const int cJ = lane & 15;

  auto clampr = [&](int r){ return r < 0 ? 0 : (r > 63 ? 63 : r); };
  bf16x8 b[4], nb[4];
  {
    const int row0 = clampr(h + 2*wv - 20);
    const short* f2r = f2pl + row0*4096;
    b[0] = load_fragX(f2r, pi, 0, 0, lane);
    b[1] = load_fragX(f2r, pi, 1, 0, lane);
    b[2] = load_fragX(f2r, pi, 0, 1, lane);
    b[3] = load_fragX(f2r, pi, 1, 1, lane);
  }
  for (int it = 0; it < 6; ++it){
    const int u = it*4 + wv;
    const int row = h + 2*u - 20;
    if (it < 5){
      const int rown = clampr(row + 8);
      const short* f2r = f2pl + rown*4096;
      nb[0] = load_fragX(f2r, pi, 0, 0, lane);
      nb[1] = load_fragX(f2r, pi, 1, 0, lane);
      nb[2] = load_fragX(f2r, pi, 0, 1, lane);
      nb[3] = load_fragX(f2r, pi, 1, 1, lane);
    }
    if (u < 21 && (unsigned)row < 64u){
      f32x4 a00 = {0.f,0.f,0.f,0.f}, a01 = a00, a10 = a00, a11 = a00;
      a00 = MFMA16(afr[0][0], b[0], a00);
      a01 = MFMA16(afr[0][0], b[1], a01);
      a10 = MFMA16(afr[1][0], b[0], a10);
      a11 = MFMA16(afr[1][0], b[1], a11);
      a00 = MFMA16(afr[0][1], b[2], a00);
      a01 = MFMA16(afr[0][1], b[3], a01);
      a10 = MFMA16(afr[1][1], b[2], a10);
      a11 = MFMA16(afr[1][1], b[3], a11);
      const int p21 = u*21;
#define SCAT(v, ii, jj) do{ int q_ = (jj) - (ii) + 10; \
        if ((unsigned)q_ < 21u) tile[(ii)*CSTA + p21 + q_] = f2bf(v); }while(0)
#pragma unroll
      for (int r = 0; r < 4; ++r){
        const int i0 = cI + r;
        SCAT(a00[r], i0,      cJ);
        SCAT(a01[r], i0,      cJ + 16);
        SCAT(a10[r], i0 + 16, cJ);
        SCAT(a11[r], i0 + 16, cJ + 16);
      }
#undef SCAT
    }
#pragma unroll
    for (int j = 0; j < 4; ++j) b[j] = nb[j];
  }
  __syncthreads();

  // BN stats partials: column sums over 32 rows; PLAIN stores (no atomics)
  {
    const int g = tid >> 2, sub = tid & 3;
    if (g < 56){
      float s[8], s2[8];
#pragma unroll
      for (int j = 0; j < 8; ++j){ s[j] = 0.f; s2[j] = 0.f; }
      for (int rr = 0; rr < 8; ++rr){
        const int row = sub*8 + rr;
        bf16x8 v = *(const bf16x8*)&tile[row*CSTA + g*8];
#pragma unroll
        for (int j = 0; j < 8; ++j){
          float f = bf2f(v[j]);
          s[j] += f; s2[j] += f*f;
        }
      }
#pragma unroll
      for (int j = 0; j < 8; ++j){
        s[j]  += __shfl_xor(s[j], 1);  s[j]  += __shfl_xor(s[j], 2);
        s2[j] += __shfl_xor(s2[j], 1); s2[j] += __shfl_xor(s2[j], 2);
      }
      if (sub == 0){
        float* ps = partS + (size_t)bi*KPAD + g*8;
        float* pq = partQ + (size_t)bi*KPAD + g*8;
        *(f32x4*)ps       = (f32x4){s[0], s[1], s[2], s[3]};
        *(f32x4*)(ps + 4) = (f32x4){s[4], s[5], s[6], s[7]};
        *(f32x4*)pq       = (f32x4){s2[0], s2[1], s2[2], s2[3]};
        *(f32x4*)(pq + 4) = (f32x4){s2[4], s2[5], s2[6], s2[7]};
      }
    }
  }

  // tile -> global: 32 rows x 56 b128 chunks
  short* cblk = corg + (size_t)bi*14336;
  for (int c = tid; c < 1792; c += 256){
    const int row = c/56, cg = c - row*56;
    *(bf16x8*)(cblk + row*KPAD + cg*8) = *(const bf16x8*)&tile[row*CSTA + cg*8];
  }
}

// k_red: fold 3584 partial slots -> sumk/ssqk[448]. Block g owns k in [g*8, g*8+8).
__global__ __launch_bounds__(256) void k_red(const float* __restrict__ partS,
    const float* __restrict__ partQ, float* __restrict__ sumk, float* __restrict__ ssqk)
{
  __shared__ float redS[4][8], redQ[4][8];
  const int tid = threadIdx.x, wv = tid >> 6, lane = tid & 63;
  const int g = blockIdx.x;
  float s[8], q[8];
#pragma unroll
  for (int j = 0; j < 8; ++j){ s[j] = 0.f; q[j] = 0.f; }
  for (int it = 0; it < 14; ++it){
    const int slot = tid + it*256;
    const float* ps = partS + (size_t)slot*KPAD + g*8;
    const float* pq = partQ + (size_t)slot*KPAD + g*8;
    f32x4 a0 = *(const f32x4*)ps, a1 = *(const f32x4*)(ps + 4);
    f32x4 b0 = *(const f32x4*)pq, b1 = *(const f32x4*)(pq + 4);
#pragma unroll
    for (int j = 0; j < 4; ++j){
      s[j] += a0[j]; s[j+4] += a1[j];
      q[j] += b0[j]; q[j+4] += b1[j];
    }
  }
#pragma unroll
  for (int off = 1; off < 64; off <<= 1){
#pragma unroll
    for (int j = 0; j < 8; ++j){
      s[j] += __shfl_xor(s[j], off);
      q[j] += __shfl_xor(q[j], off);
    }
  }
  if (lane == 0){
#pragma unroll
    for (int j = 0; j < 8; ++j){ redS[wv][j] = s[j]; redQ[wv][j] = q[j]; }
  }
  __syncthreads();
  if (tid < 8){
    sumk[g*8 + tid] = redS[0][tid] + redS[1][tid] + redS[2][tid] + redS[3][tid];
    ssqk[g*8 + tid] = redQ[0][tid] + redQ[1][tid] + redQ[2][tid] + redQ[3][tid];
  }
}

// k_finalizeC: BN scale/shift from sumk/ssqk -> wpT (bf16) + bias
__global__ __launch_bounds__(256) void k_finalizeC(const float* __restrict__ sumk,
    const float* __restrict__ ssqk, const float* __restrict__ gamma,
    const float* __restrict__ beta, const float* __restrict__ convw,
    short* __restrict__ wpT, float* __restrict__ bias)
{
  __shared__ float s_scale[NPQ], s_shift[NPQ];
  const int tid = threadIdx.x;
  for (int k = tid; k < NPQ; k += 256){
    float m  = sumk[k] * (1.f/114688.f);
    float v  = ssqk[k] * (1.f/114688.f) - m*m;
    float iv = rsqrtf(v + 1e-5f);
    float sc = gamma[k] * iv;
    s_scale[k] = sc;
    s_shift[k] = beta[k] - m*sc;
  }
  __syncthreads();
  for (int idx = tid; idx < 64*KPAD; idx += 256){
    int o = idx / KPAD, k = idx - o*KPAD;
    float w = (k < NPQ) ? convw[o*NPQ + k] * s_scale[k] : 0.f;
    wpT[idx] = f2bf(w);
  }
  if (tid < 64){
    float b = 0.f;
    for (int k = 0; k < NPQ; ++k) b += s_shift[k] * convw[tid*NPQ + k];
    bias[tid] = b;
  }
}

// k_main2: stage cor tile from global (pixel-reordered), GEMM2, coalesced epilogue
__global__ __launch_bounds__(256,2) void k_main2(const short* __restrict__ corg,
    const short* __restrict__ wpT, const float* __restrict__ bias,
    float* __restrict__ out)
{
  __shared__ __align__(16) short cor[64*CSTR];
  const int tid = threadIdx.x, wv = tid >> 6, lane = tid & 63;
  const int nn = blockIdx.x >> 6, h = blockIdx.x & 63;
  const int pl1g = (nn/7)*8 + (nn%7);
  const short* cblk = corg + (size_t)(nn*64 + h)*28672;

#pragma unroll
  for (int s = 0; s < 14; ++s){
    const int c = tid + s*256;
    const int rho = c/56, cg = c - rho*56;
    const int w = ((rho & 31) << 1) | (rho >> 5);
    bf16x8 v = *(const bf16x8*)(cblk + c*8);
    *(bf16x8*)&cor[w*CSTR + cg*8] = v;
  }
  __syncthreads();

  const int m = lane & 15, kg = lane >> 4;
  const short* wrow = wpT + (wv*16 + m)*KPAD;
  f32x4 acc[4];
#pragma unroll
  for (int nt = 0; nt < 4; ++nt) acc[nt] = (f32x4){0.f,0.f,0.f,0.f};
  for (int kk = 0; kk < 14; ++kk){
    const int k0 = kk*32 + kg*8;
    bf16x8 aw = *(const bf16x8*)(wrow + k0);
#pragma unroll
    for (int nt = 0; nt < 4; ++nt){
      bf16x8 bc = *(const bf16x8*)&cor[(nt*16 + m)*CSTR + k0];
      acc[nt] = MFMA16(aw, bc, acc[nt]);
    }
  }
  const int r0 = (lane >> 4)*4;
  float bo[4];
#pragma unroll
  for (int r = 0; r < 4; ++r) bo[r] = bias[wv*16 + r0 + r];
  float* outb = out + (size_t)pl1g*CHW + h*64;
#pragma unroll
  for (int nt = 0; nt < 4; ++nt)
#pragma unroll
    for (int r = 0; r < 4; ++r){
      const int o = wv*16 + r0 + r;
      outb[o*HW + nt*16 + m] = acc[nt][r] + bo[r];
    }
}

// ======================= R6 TIER (atomics, verified) =======================
__global__ __launch_bounds__(256,4) void k_cor(const short* __restrict__ X,
    short* __restrict__ corg, float* __restrict__ gpartS, float* __restrict__ gpartQ)
{
  __shared__ __align__(16) short tile[32*CSTA];
  const int tid = threadIdx.x, wv = tid >> 6, lane = tid & 63;
  const int bi = blockIdx.x;
  const int pi = bi & 1, h = (bi >> 1) & 63, nn = bi >> 7;
  const int pl1 = (nn/7)*8 + (nn%7);
  const short* f1r  = X + ((size_t)pl1*64 + h)*4096;
  const short* f2pl = X + (size_t)(pl1 + 1)*64*4096;

  {
    int4 z = {0,0,0,0};
    for (int idx = tid; idx < 32*CSTA/8; idx += 256) ((int4*)tile)[idx] = z;
  }
  bf16x8 afr[2][2];
#pragma unroll
  for (int mt = 0; mt < 2; ++mt)
#pragma unroll
    for (int kk = 0; kk < 2; ++kk)
      afr[mt][kk] = load_fragX(f1r, pi, mt, kk, lane);
  __syncthreads();
  const int cI = (lane >> 4)*4;
  const int cJ = lane & 15;
  auto clampr = [&](int r){ return r < 0 ? 0 : (r > 63 ? 63 : r); };
  bf16x8 b[4], nb[4];
  {
    const int row0 = clampr(h + 2*wv - 20);
    const short* f2r = f2pl + row0*4096;
    b[0] = load_fragX(f2r, pi, 0, 0, lane);
    b[1] = load_fragX(f2r, pi, 1, 0, lane);
    b[2] = load_fragX(f2r, pi, 0, 1, lane);
    b[3] = load_fragX(f2r, pi, 1, 1, lane);
  }
  for (int it = 0; it < 6; ++it){
    const int u = it*4 + wv;
    const int row = h + 2*u - 20;
    if (it < 5){
      const int rown = clampr(row + 8);
      const short* f2r = f2pl + rown*4096;
      nb[0] = load_fragX(f2r, pi, 0, 0, lane);
      nb[1] = load_fragX(f2r, pi, 1, 0, lane);
      nb[2] = load_fragX(f2r, pi, 0, 1, lane);
      nb[3] = load_fragX(f2r, pi, 1, 1, lane);
    }
    if (u < 21 && (unsigned)row < 64u){
      f32x4 a00 = {0.f,0.f,0.f,0.f}, a01 = a00, a10 = a00, a11 = a00;
      a00 = MFMA16(afr[0][0], b[0], a00);
      a01 = MFMA16(afr[0][0], b[1], a01);
      a10 = MFMA16(afr[1][0], b[0], a10);
      a11 = MFMA16(afr[1][0], b[1], a11);
      a00 = MFMA16(afr[0][1], b[2], a00);
      a01 = MFMA16(afr[0][1], b[3], a01);
      a10 = MFMA16(afr[1][1], b[2], a10);
      a11 = MFMA16(afr[1][1], b[3], a11);
      const int p21 = u*21;
#define SCAT(v, ii, jj) do{ int q_ = (jj) - (ii) + 10; \
        if ((unsigned)q_ < 21u) tile[(ii)*CSTA + p21 + q_] = f2bf(v); }while(0)
#pragma unroll
      for (int r = 0; r < 4; ++r){
        const int i0 = cI + r;
        SCAT(a00[r], i0,      cJ);
        SCAT(a01[r], i0,      cJ + 16);
        SCAT(a10[r], i0 + 16, cJ);
        SCAT(a11[r], i0 + 16, cJ + 16);
      }
#undef SCAT
    }
#pragma unroll
    for (int j = 0; j < 4; ++j) b[j] = nb[j];
  }
  __syncthreads();
  {
    const int g = tid >> 2, sub = tid & 3;
    if (g < 56){
      float s[8], s2[8];
#pragma unroll
      for (int j = 0; j < 8; ++j){ s[j] = 0.f; s2[j] = 0.f; }
      for (int rr = 0; rr < 8; ++rr){
        const int row = sub*8 + rr;
        bf16x8 v = *(const bf16x8*)&tile[row*CSTA + g*8];
#pragma unroll
        for (int j = 0; j < 8; ++j){
          float f = bf2f(v[j]);
          s[j] += f; s2[j] += f*f;
        }
      }
#pragma unroll
      for (int j = 0; j < 8; ++j){
        s[j]  += __shfl_xor(s[j], 1);  s[j]  += __shfl_xor(s[j], 2);
        s2[j] += __shfl_xor(s2[j], 1); s2[j] += __shfl_xor(s2[j], 2);
      }
      if (sub == 0){
        const int slot = (bi & 31)*KPAD + g*8;
#pragma unroll
        for (int j = 0; j < 8; ++j){
          atomicAdd(&gpartS[slot + j], s[j]);
          atomicAdd(&gpartQ[slot + j], s2[j]);
        }
      }
    }
  }
  short* cblk = corg + (size_t)bi*14336;
  for (int c = tid; c < 1792; c += 256){
    const int row = c/56, cg = c - row*56;
    *(bf16x8*)(cblk + row*KPAD + cg*8) = *(const bf16x8*)&tile[row*CSTA + cg*8];
  }
}

__global__ __launch_bounds__(256) void k_finalizeB(const float* __restrict__ gpartS,
    const float* __restrict__ gpartQ, const float* __restrict__ gamma,
    const float* __restrict__ beta, const float* __restrict__ convw,
    short* __restrict__ wpT, float* __restrict__ bias)
{
  __shared__ float s_scale[NPQ], s_shift[NPQ];
  const int tid = threadIdx.x;
  for (int k = tid; k < NPQ; k += 256){
    float s = 0.f, q = 0.f;
    for (int sl = 0; sl < 32; ++sl){
      s += gpartS[sl*KPAD + k];
      q += gpartQ[sl*KPAD + k];
    }
    float m  = s * (1.f/114688.f);
    float v  = q * (1.f/114688.f) - m*m;
    float iv = rsqrtf(v + 1e-5f);
    float sc = gamma[k] * iv;
    s_scale[k] = sc;
    s_shift[k] = beta[k] - m*sc;
  }
  __syncthreads();
  for (int idx = tid; idx < 64*KPAD; idx += 256){
    int o = idx / KPAD, k = idx - o*KPAD;
    float w = (k < NPQ) ? convw[o*NPQ + k] * s_scale[k] : 0.f;
    wpT[idx] = f2bf(w);
  }
  if (tid < 64){
    float b = 0.f;
    for (int k = 0; k < NPQ; ++k) b += s_shift[k] * convw[tid*NPQ + k];
    bias[tid] = b;
  }
}

// ======================= R4 FALLBACK =======================
__global__ __launch_bounds__(256,2) void k_stats(const short* __restrict__ X,
                                                 float* __restrict__ gsum,
                                                 float* __restrict__ gssq,
                                                 int n0, int plane0)
{
  __shared__ float Gbuf[4*1056];
  __shared__ float s_sum[2][NPQ];
  __shared__ float s_ssq[2][NPQ];
  const int tid = threadIdx.x, wv = tid >> 6, lane = tid & 63;
  const int nn = n0 + (blockIdx.x >> 6), h = blockIdx.x & 63;
  const int pl1 = (nn/7)*8 + (nn%7) - plane0;
  const short* f1r  = X + ((size_t)pl1*64 + h)*4096;
  const short* f2pl = X + (size_t)(pl1 + 1)*64*4096;
  float* Gw = Gbuf + wv*1056;

  for (int i = tid; i < 2*NPQ; i += 256){
    (&s_sum[0][0])[i] = 0.f; (&s_ssq[0][0])[i] = 0.f;
  }
  __syncthreads();

  bf16x8 afr[2][2];
  int cur_pi = -1;
  for (int it = 0; it < 11; ++it){
    const int u = it*4 + wv;
    const bool active = (u < 42);
    const int pi = (u >= 21) ? 1 : 0;
    const int p  = u - pi*21;
    const int row = h + 2*p - 20;
    const bool rv = active && ((unsigned)row < 64u);

    if (active && pi != cur_pi){
#pragma unroll
      for (int mt = 0; mt < 2; ++mt)
#pragma unroll
        for (int kk = 0; kk < 2; ++kk)
          afr[mt][kk] = load_fragX(f1r, pi, mt, kk, lane);
      cur_pi = pi;
    }
    if (rv){
      const short* f2r = f2pl + row*4096;
      f32x4 a00 = {0.f,0.f,0.f,0.f}, a01 = a00, a10 = a00, a11 = a00;
#pragma unroll
      for (int kk = 0; kk < 2; ++kk){
        bf16x8 b0 = load_fragX(f2r, pi, 0, kk, lane);
        bf16x8 b1 = load_fragX(f2r, pi, 1, kk, lane);
        a00 = MFMA16(afr[0][kk], b0, a00);
        a01 = MFMA16(afr[0][kk], b1, a01);
        a10 = MFMA16(afr[1][kk], b0, a10);
        a11 = MFMA16(afr[1][kk], b1, a11);
      }
      const int cI = (lane >> 4)*4;
      const int cJ = lane & 15;
#pragma unroll
      for (int r = 0; r < 4; ++r){
        Gw[(cJ     )*33 + cI + r     ] = a00[r];
        Gw[(cJ + 16)*33 + cI + r     ] = a01[r];
        Gw[(cJ     )*33 + cI + r + 16] = a10[r];
        Gw[(cJ + 16)*33 + cI + r + 16] = a11[r];
      }
    }
    __syncthreads();
    if (rv){
      const int q = lane / 3;
      const int seg = lane - q*3;
      float s = 0.f, s2 = 0.f;
      if (lane < 63){
        const int i0 = seg*11;
        const int i1 = (seg == 2) ? 32 : i0 + 11;
        for (int i = i0; i < i1; ++i){
          const int j = i + q - 10;
          if ((unsigned)j < 32u){
            float v = Gw[j*33 + i];
            s += v; s2 += v*v;
          }
        }
      }
      float sA = __shfl(s,  lane+1), sB = __shfl(s,  lane+2);
      float tA = __shfl(s2, lane+1), tB = __shfl(s2, lane+2);
      if (lane < 63 && seg == 0){
        s_sum[pi][p*21 + q] += s + sA + sB;
        s_ssq[pi][p*21 + q] += s2 + tA + tB;
      }
    }
  }
  __syncthreads();
  for (int i = tid; i < NPQ; i += 256){
    atomicAdd(&gsum[i], s_sum[0][i] + s_sum[1][i]);
    atomicAdd(&gssq[i], s_ssq[0][i] + s_ssq[1][i]);
  }
}

__global__ __launch_bounds__(256) void k_finalizeA(const float* __restrict__ gsum,
    const float* __restrict__ gssq, const float* __restrict__ gamma,
    const float* __restrict__ beta, const float* __restrict__ convw,
    short* __restrict__ wpT, float* __restrict__ bias)
{
  __shared__ float s_scale[NPQ], s_shift[NPQ];
  const int tid = threadIdx.x;
  for (int k = tid; k < NPQ; k += 256){
    float m  = gsum[k] * (1.f/114688.f);
    float v  = gssq[k] * (1.f/114688.f) - m*m;
    float iv = rsqrtf(v + 1e-5f);
    float sc = gamma[k] * iv;
    s_scale[k] = sc;
    s_shift[k] = beta[k] - m*sc;
  }
  __syncthreads();
  for (int idx = tid; idx < 64*KPAD; idx += 256){
    int o = idx / KPAD, k = idx - o*KPAD;
    float w = (k < NPQ) ? convw[o*NPQ + k] * s_scale[k] : 0.f;
    wpT[idx] = f2bf(w);
  }
  if (tid < 64){
    float b = 0.f;
    for (int k = 0; k < NPQ; ++k) b += s_shift[k] * convw[tid*NPQ + k];
    bias[tid] = b;
  }
}

__global__ __launch_bounds__(256,2) void k_main(const short* __restrict__ X,
    const short* __restrict__ wpT, const float* __restrict__ bias,
    float* __restrict__ out, int n0, int plane0)
{
  __shared__ __align__(16) short cor[64*CSTR];
  const int tid = threadIdx.x, wv = tid >> 6, lane = tid & 63;
  const int nn = n0 + (blockIdx.x >> 6), h = blockIdx.x & 63;
  const int pl1g = (nn/7)*8 + (nn%7);
  const int pl1 = pl1g - plane0;
  const short* f1r  = X + ((size_t)pl1*64 + h)*4096;
  const short* f2pl = X + (size_t)(pl1 + 1)*64*4096;

  {
    int4 z = {0,0,0,0};
    for (int idx = tid; idx < 64*CSTR/8; idx += 256) ((int4*)cor)[idx] = z;
  }
  __syncthreads();

  bf16x8 afr[2][2];
  int cur_pi = -1;
  for (int it = 0; it < 11; ++it){
    const int u = it*4 + wv;
    const bool active = (u < 42);
    const int pi = (u >= 21) ? 1 : 0;
    const int p  = u - pi*21;
    const int row = h + 2*p - 20;
    const bool rv = active && ((unsigned)row < 64u);

    if (active && pi != cur_pi){
#pragma unroll
      for (int mt = 0; mt < 2; ++mt)
#pragma unroll
        for (int kk = 0; kk < 2; ++kk)
          afr[mt][kk] = load_fragX(f1r, pi, mt, kk, lane);
      cur_pi = pi;
    }
    if (rv){
      const short* f2r = f2pl + row*4096;
      f32x4 a00 = {0.f,0.f,0.f,0.f}, a01 = a00, a10 = a00, a11 = a00;
#pragma unroll
      for (int kk = 0; kk < 2; ++kk){
        bf16x8 b0 = load_fragX(f2r, pi, 0, kk, lane);
        bf16x8 b1 = load_fragX(f2r, pi, 1, kk, lane);
        a00 = MFMA16(afr[0][kk], b0, a00);
        a01 = MFMA16(afr[0][kk], b1, a01);
        a10 = MFMA16(afr[1][kk], b0, a10);
        a11 = MFMA16(afr[1][kk], b1, a11);
      }
      const int cI = (lane >> 4)*4;
      const int cJ = lane & 15;
      const int p21 = p*21;
#define SCAT(v, ii, jj) do{ int q_ = (jj) - (ii) + 10; \
        if ((unsigned)q_ < 21u) cor[(2*(ii)+pi)*CSTR + p21 + q_] = f2bf(v); }while(0)
#pragma unroll
      for (int r = 0; r < 4; ++r){
        const int i0 = cI + r;
        SCAT(a00[r], i0,      cJ);
        SCAT(a01[r], i0,      cJ + 16);
        SCAT(a10[r], i0 + 16, cJ);
        SCAT(a11[r], i0 + 16, cJ + 16);
      }
#undef SCAT
    }
  }
  __syncthreads();

  const int m = lane & 15, kg = lane >> 4;
  const short* wrow = wpT + (wv*16 + m)*KPAD;
  f32x4 acc[4];
#pragma unroll
  for (int nt = 0; nt < 4; ++nt) acc[nt] = (f32x4){0.f,0.f,0.f,0.f};
  for (int kk = 0; kk < 14; ++kk){
    const int k0 = kk*32 + kg*8;
    bf16x8 aw = *(const bf16x8*)(wrow + k0);
#pragma unroll
    for (int nt = 0; nt < 4; ++nt){
      bf16x8 bc = *(const bf16x8*)&cor[(nt*16 + m)*CSTR + k0];
      acc[nt] = MFMA16(aw, bc, acc[nt]);
    }
  }
  const int r0 = (lane >> 4)*4;
  float bo[4];
#pragma unroll
  for (int r = 0; r < 4; ++r) bo[r] = bias[wv*16 + r0 + r];
  float* outb = out + (size_t)pl1g*CHW + h*64;
#pragma unroll
  for (int nt = 0; nt < 4; ++nt)
#pragma unroll
    for (int r = 0; r < 4; ++r){
      const int o = wv*16 + r0 + r;
      outb[o*HW + nt*16 + m] = acc[nt][r] + bo[r];
    }
}

// ---------------- zero frame T=7 ----------------
__global__ __launch_bounds__(256) void k_zero(float* __restrict__ out){
  const int idx = blockIdx.x*256 + threadIdx.x;
  const int b = idx >> 16, r = idx & 65535;
  float4* p = (float4*)(out + (size_t)(b*8 + 7)*CHW);
  p[r] = make_float4(0.f, 0.f, 0.f, 0.f);
}

extern "C" void kernel_launch(void* const* d_in, const int* in_sizes, int n_in,
                              void* d_out, int out_size, void* d_ws, size_t ws_size,
                              hipStream_t stream)
{
  const float* feats = (const float*)d_in[0];
  const float* gamma = (const float*)d_in[1];
  const float* beta  = (const float*)d_in[2];
  const float* convw = (const float*)d_in[3];
  float* out = (float*)d_out;
  float* wsf = (float*)d_ws;

  k_zero<<<1024, 256, 0, stream>>>(out);

  // ---- Tier P: per-block partials, no global atomics (floats offsets) ----
  {
    float* sumk  = wsf;                        // [0,448)
    float* ssqk  = wsf + 448;                  // [448,896)
    float* biasB = wsf + 896;                  // [896,960)
    short* wpTB  = (short*)(wsf + 1024);       // 28672 shorts = 14336 floats: [1024,15360)
    float* partS = wsf + 15360;                // 3584*448 = 1605632: [15360, 1620992)
    float* partQ = wsf + 1620992;              // [1620992, 3226624)
    short* Xn    = (short*)(wsf + 3226624);    // 8388608 shorts = 4194304 fl: [3226624, 7420928)
    short* corg  = (short*)(wsf + 7420928);    // 51380224 shorts: [7420928, 33111040)
    const size_t need_p = (size_t)33111040*4;
    if (ws_size >= need_p){
      k_transpose<<<2048, 256, 0, stream>>>(feats, Xn, 0);
      k_cor2<<<3584, 256, 0, stream>>>(Xn, corg, partS, partQ);
      k_red<<<56, 256, 0, stream>>>(partS, partQ, sumk, ssqk);
      k_finalizeC<<<1, 256, 0, stream>>>(sumk, ssqk, gamma, beta, convw, wpTB, biasB);
      k_main2<<<1792, 256, 0, stream>>>(corg, wpTB, biasB, out);
      return;
    }
  }

  // ---- Tier A: R6 atomic path (verified) ----
  {
    float* gpartS = wsf;                       // [0, 14336)
    float* gpartQ = wsf + 14336;               // [14336, 28672)
    float* biasB  = wsf + 28672;
    short* wpTB   = (short*)(wsf + 28736);     // [28736, 43072)
    short* Xn     = (short*)(wsf + 43072);
    short* corg   = (short*)(wsf + 4237376);
    const size_t need_a = (size_t)4237376*4 + (size_t)3584*14336*2;
    if (ws_size >= need_a){
      hipMemsetAsync(gpartS, 0, 2*14336*sizeof(float), stream);
      k_transpose<<<2048, 256, 0, stream>>>(feats, Xn, 0);
      k_cor<<<3584, 256, 0, stream>>>(Xn, corg, gpartS, gpartQ);
      k_finalizeB<<<1, 256, 0, stream>>>(gpartS, gpartQ, gamma, beta, convw, wpTB, biasB);
      k_main2<<<1792, 256, 0, stream>>>(corg, wpTB, biasB, out);
      return;
    }
  }

  // ---- R4 fallback ----
  float* gsum = wsf;
  float* gssq = wsf + 441;
  float* bias = wsf + 896;
  short* wpT  = (short*)(wsf + 1024);
  short* X    = (short*)(wsf + 16384);
  const size_t fixedB = 16384*sizeof(float);
  const size_t planeB = (size_t)CHW*2;

  hipMemsetAsync(gsum, 0, 882*sizeof(float), stream);
  if (ws_size >= fixedB + 32*planeB){
    k_transpose<<<2048, 256, 0, stream>>>(feats, X, 0);
    k_stats<<<1792, 256, 0, stream>>>(X, gsum, gssq, 0, 0);
    k_finalizeA<<<1, 256, 0, stream>>>(gsum, gssq, gamma, beta, convw, wpT, bias);
    k_main<<<1792, 256, 0, stream>>>(X, wpT, bias, out, 0, 0);
  } else if (ws_size >= fixedB + 8*planeB){
    for (int b = 0; b < 4; ++b){
      k_transpose<<<512, 256, 0, stream>>>(feats, X, b*8);
      k_stats<<<448, 256, 0, stream>>>(X, gsum, gssq, b*7, b*8);
    }
    k_finalizeA<<<1, 256, 0, stream>>>(gsum, gssq, gamma, beta, convw, wpT, bias);
    for (int b = 0; b < 4; ++b){
      k_transpose<<<512, 256, 0, stream>>>(feats, X, b*8);
      k_main<<<448, 256, 0, stream>>>(X, wpT, bias, out, b*7, b*8);
    }
  } else {
    for (int n = 0; n < 28; ++n){
      const int pl = (n/7)*8 + (n%7);
      k_transpose<<<128, 256, 0, stream>>>(feats, X, pl);
      k_stats<<<64, 256, 0, stream>>>(X, gsum, gssq, n, pl);
    }
    k_finalizeA<<<1, 256, 0, stream>>>(gsum, gssq, gamma, beta, convw, wpT, bias);
    for (int n = 0; n < 28; ++n){
      const int pl = (n/7)*8 + (n%7);
      k_transpose<<<128, 256, 0, stream>>>(feats, X, pl);
      k_main<<<64, 256, 0, stream>>>(X, wpT, bias, out, n, pl);
    }
  }
}

// Round 8
// 189.805 us; speedup vs baseline: 1.5652x; 1.3120x over previous
//
#include <hip/hip_runtime.h>

#define HW   4096
#define CHW  262144
#define NPQ  441
#define KPAD 448
#define CSTR 456   // k_main/k_main2 LDS cor row stride (shorts)
#define CSTA 460   // k_cor LDS tile row stride (shorts)

typedef __attribute__((ext_vector_type(8))) short bf16x8;
typedef __attribute__((ext_vector_type(4))) float f32x4;

#define MFMA16(a,b,c) __builtin_amdgcn_mfma_f32_16x16x32_bf16(a,b,c,0,0,0)

__device__ __forceinline__ short f2bf(float f){
  unsigned u = __float_as_uint(f);
  return (short)((u + 0x7FFFu + ((u >> 16) & 1u)) >> 16);
}
__device__ __forceinline__ float bf2f(short s){
  return __uint_as_float(((unsigned)(unsigned short)s) << 16);
}

__device__ __forceinline__ bf16x8 load_fragX(const short* rowX, int pi, int tile,
                                             int kk, int lane){
  const int m = lane & 15, kg = lane >> 4;
  return *(const bf16x8*)(rowX + (2*(tile*16 + m) + pi)*64 + kk*32 + kg*8);
}

// ---------------- Pass 0: fp32 [pl][c][h][w] -> bf16 X[pl-plane0][h][w][c] ----------------
__global__ __launch_bounds__(256,4) void k_transpose(const float* __restrict__ feats,
                                                     short* __restrict__ X, int plane0)
{
  __shared__ float tile[64*65];
  const int tid = threadIdx.x;
  const int pll = blockIdx.x >> 6, h = blockIdx.x & 63;
  const float* pb = feats + (size_t)(plane0 + pll)*CHW + h*64;
#pragma unroll
  for (int k = 0; k < 4; ++k){
    const int idx = tid + k*256;
    const int c = idx >> 4, w4 = idx & 15;
    f32x4 v = *(const f32x4*)(pb + c*HW + w4*4);
#pragma unroll
    for (int j = 0; j < 4; ++j) tile[c*65 + w4*4 + j] = v[j];
  }
  __syncthreads();
  short* xb = X + ((size_t)pll*64 + h)*4096;
#pragma unroll
  for (int s = 0; s < 2; ++s){
    const int chunk = tid + s*256;
    const int w = chunk >> 3, cg = chunk & 7;
    bf16x8 r;
#pragma unroll
    for (int j = 0; j < 8; ++j) r[j] = f2bf(tile[(cg*8 + j)*65 + w]);
    *(bf16x8*)(xb + w*64 + cg*8) = r;
  }
}

// ======================= PREFERRED PATH (no global atomics) =======================
// k_cor2: Gram -> band tile -> column-sum partials (PLAIN stores) + corg writeback.
__global__ __launch_bounds__(256,4) void k_cor2(const short* __restrict__ X,
    short* __restrict__ corg, float* __restrict__ partS, float* __restrict__ partQ)
{
  __shared__ __align__(16) short tile[32*CSTA];
  const int tid = threadIdx.x, wv = tid >> 6, lane = tid & 63;
  const int bi = blockIdx.x;
  const int pi = bi & 1, h = (bi >> 1) & 63, nn = bi >> 7;
  const int pl1 = (nn/7)*8 + (nn%7);
  const short* f1r  = X + ((size_t)pl1*64 + h)*4096;
  const short* f2pl = X + (size_t)(pl1 + 1)*64*4096;

  {
    int4 z = {0,0,0,0};
    for (int idx = tid; idx < 32*CSTA/8; idx += 256) ((int4*)tile)[idx] = z;
  }

  bf16x8 afr[2][2];
#pragma unroll
  for (int mt = 0; mt < 2; ++mt)
#pragma unroll
    for (int kk = 0; kk < 2; ++kk)
      afr[mt][kk] = load_fragX(f1r, pi, mt, kk, lane);

  __syncthreads();

  const int cI = (lane >> 4)*4;
  const int cJ = lane & 15;

  auto clampr = [&](int r){ return r < 0 ? 0 : (r > 63 ? 63 : r); };
  bf16x8 b[4], nb[4];
  {
    const int row0 = clampr(h + 2*wv - 20);
    const short* f2r = f2pl + row0*4096;
    b[0] = load_fragX(f2r, pi, 0, 0, lane);
    b[1] = load_fragX(f2r, pi, 1, 0, lane);
    b[2] = load_fragX(f2r, pi, 0, 1, lane);
    b[3] = load_fragX(f2r, pi, 1, 1, lane);
  }
  for (int it = 0; it < 6; ++it){
    const int u = it*4 + wv;
    const int row = h + 2*u - 20;
    if (it < 5){
      const int rown = clampr(row + 8);
      const short* f2r = f2pl + rown*4096;
      nb[0] = load_fragX(f2r, pi, 0, 0, lane);
      nb[1] = load_fragX(f2r, pi, 1, 0, lane);
      nb[2] = load_fragX(f2r, pi, 0, 1, lane);
      nb[3] = load_fragX(f2r, pi, 1, 1, lane);
    }
    if (u < 21 && (unsigned)row < 64u){
      f32x4 a00 = {0.f,0.f,0.f,0.f}, a01 = a00, a10 = a00, a11 = a00;
      a00 = MFMA16(afr[0][0], b[0], a00);
      a01 = MFMA16(afr[0][0], b[1], a01);
      a10 = MFMA16(afr[1][0], b[0], a10);
      a11 = MFMA16(afr[1][0], b[1], a11);
      a00 = MFMA16(afr[0][1], b[2], a00);
      a01 = MFMA16(afr[0][1], b[3], a01);
      a10 = MFMA16(afr[1][1], b[2], a10);
      a11 = MFMA16(afr[1][1], b[3], a11);
      const int p21 = u*21;
#define SCAT(v, ii, jj) do{ int q_ = (jj) - (ii) + 10; \
        if ((unsigned)q_ < 21u) tile[(ii)*CSTA + p21 + q_] = f2bf(v); }while(0)
#pragma unroll
      for (int r = 0; r < 4; ++r){
        const int i0 = cI + r;
        SCAT(a00[r], i0,      cJ);
        SCAT(a01[r], i0,      cJ + 16);
        SCAT(a10[r], i0 + 16, cJ);
        SCAT(a11[r], i0 + 16, cJ + 16);
      }
#undef SCAT
    }
#pragma unroll
    for (int j = 0; j < 4; ++j) b[j] = nb[j];
  }
  __syncthreads();

  // BN stats partials: column sums over 32 rows; PLAIN stores (no atomics)
  {
    const int g = tid >> 2, sub = tid & 3;
    if (g < 56){
      float s[8], s2[8];
#pragma unroll
      for (int j = 0; j < 8; ++j){ s[j] = 0.f; s2[j] = 0.f; }
      for (int rr = 0; rr < 8; ++rr){
        const int row = sub*8 + rr;
        bf16x8 v = *(const bf16x8*)&tile[row*CSTA + g*8];
#pragma unroll
        for (int j = 0; j < 8; ++j){
          float f = bf2f(v[j]);
          s[j] += f; s2[j] += f*f;
        }
      }
#pragma unroll
      for (int j = 0; j < 8; ++j){
        s[j]  += __shfl_xor(s[j], 1);  s[j]  += __shfl_xor(s[j], 2);
        s2[j] += __shfl_xor(s2[j], 1); s2[j] += __shfl_xor(s2[j], 2);
      }
      if (sub == 0){
        float* ps = partS + (size_t)bi*KPAD + g*8;
        float* pq = partQ + (size_t)bi*KPAD + g*8;
        *(f32x4*)ps       = (f32x4){s[0], s[1], s[2], s[3]};
        *(f32x4*)(ps + 4) = (f32x4){s[4], s[5], s[6], s[7]};
        *(f32x4*)pq       = (f32x4){s2[0], s2[1], s2[2], s2[3]};
        *(f32x4*)(pq + 4) = (f32x4){s2[4], s2[5], s2[6], s2[7]};
      }
    }
  }

  // tile -> global: 32 rows x 56 b128 chunks
  short* cblk = corg + (size_t)bi*14336;
  for (int c = tid; c < 1792; c += 256){
    const int row = c/56, cg = c - row*56;
    *(bf16x8*)(cblk + row*KPAD + cg*8) = *(const bf16x8*)&tile[row*CSTA + cg*8];
  }
}

// k_red2: fold 3584 partial slots AND compute BN scale/shift for 8 k's per block.
__global__ __launch_bounds__(256) void k_red2(const float* __restrict__ partS,
    const float* __restrict__ partQ, const float* __restrict__ gamma,
    const float* __restrict__ beta, float* __restrict__ scalek,
    float* __restrict__ shiftk)
{
  __shared__ float redS[4][8], redQ[4][8];
  const int tid = threadIdx.x, wv = tid >> 6, lane = tid & 63;
  const int g = blockIdx.x;
  float s[8], q[8];
#pragma unroll
  for (int j = 0; j < 8; ++j){ s[j] = 0.f; q[j] = 0.f; }
  for (int it = 0; it < 14; ++it){
    const int slot = tid + it*256;
    const float* ps = partS + (size_t)slot*KPAD + g*8;
    const float* pq = partQ + (size_t)slot*KPAD + g*8;
    f32x4 a0 = *(const f32x4*)ps, a1 = *(const f32x4*)(ps + 4);
    f32x4 b0 = *(const f32x4*)pq, b1 = *(const f32x4*)(pq + 4);
#pragma unroll
    for (int j = 0; j < 4; ++j){
      s[j] += a0[j]; s[j+4] += a1[j];
      q[j] += b0[j]; q[j+4] += b1[j];
    }
  }
#pragma unroll
  for (int off = 1; off < 64; off <<= 1){
#pragma unroll
    for (int j = 0; j < 8; ++j){
      s[j] += __shfl_xor(s[j], off);
      q[j] += __shfl_xor(q[j], off);
    }
  }
  if (lane == 0){
#pragma unroll
    for (int j = 0; j < 8; ++j){ redS[wv][j] = s[j]; redQ[wv][j] = q[j]; }
  }
  __syncthreads();
  if (tid < 8){
    const int k = g*8 + tid;
    float st = redS[0][tid] + redS[1][tid] + redS[2][tid] + redS[3][tid];
    float qt = redQ[0][tid] + redQ[1][tid] + redQ[2][tid] + redQ[3][tid];
    float m  = st * (1.f/114688.f);
    float v  = qt * (1.f/114688.f) - m*m;
    float iv = rsqrtf(v + 1e-5f);
    float gm = (k < NPQ) ? gamma[k] : 0.f;
    float bt = (k < NPQ) ? beta[k]  : 0.f;
    float sc = gm * iv;
    scalek[k] = sc;            // 0 for pad k
    shiftk[k] = bt - m*sc;     // 0 for pad k
  }
}

// k_wfold: one block per output channel o — fold scale into weights + bias reduce.
__global__ __launch_bounds__(256) void k_wfold(const float* __restrict__ scalek,
    const float* __restrict__ shiftk, const float* __restrict__ convw,
    short* __restrict__ wpT, float* __restrict__ bias)
{
  __shared__ float red[4];
  const int o = blockIdx.x, tid = threadIdx.x, wv = tid >> 6, lane = tid & 63;
  float part = 0.f;
#pragma unroll
  for (int s = 0; s < 2; ++s){
    const int k = tid + s*256;
    if (k < KPAD){
      float cw = (k < NPQ) ? convw[o*NPQ + k] : 0.f;
      wpT[o*KPAD + k] = f2bf(cw * scalek[k]);
      part += cw * shiftk[k];
    }
  }
#pragma unroll
  for (int off = 1; off < 64; off <<= 1) part += __shfl_xor(part, off);
  if (lane == 0) red[wv] = part;
  __syncthreads();
  if (tid == 0) bias[o] = red[0] + red[1] + red[2] + red[3];
}

// k_main2: stage cor tile from global (pixel-reordered), GEMM2, coalesced epilogue
__global__ __launch_bounds__(256,2) void k_main2(const short* __restrict__ corg,
    const short* __restrict__ wpT, const float* __restrict__ bias,
    float* __restrict__ out)
{
  __shared__ __align__(16) short cor[64*CSTR];
  const int tid = threadIdx.x, wv = tid >> 6, lane = tid & 63;
  const int nn = blockIdx.x >> 6, h = blockIdx.x & 63;
  const int pl1g = (nn/7)*8 + (nn%7);
  const short* cblk = corg + (size_t)(nn*64 + h)*28672;

#pragma unroll
  for (int s = 0; s < 14; ++s){
    const int c = tid + s*256;
    const int rho = c/56, cg = c - rho*56;
    const int w = ((rho & 31) << 1) | (rho >> 5);
    bf16x8 v = *(const bf16x8*)(cblk + c*8);
    *(bf16x8*)&cor[w*CSTR + cg*8] = v;
  }
  __syncthreads();

  const int m = lane & 15, kg = lane >> 4;
  const short* wrow = wpT + (wv*16 + m)*KPAD;
  f32x4 acc[4];
#pragma unroll
  for (int nt = 0; nt < 4; ++nt) acc[nt] = (f32x4){0.f,0.f,0.f,0.f};
  for (int kk = 0; kk < 14; ++kk){
    const int k0 = kk*32 + kg*8;
    bf16x8 aw = *(const bf16x8*)(wrow + k0);
#pragma unroll
    for (int nt = 0; nt < 4; ++nt){
      bf16x8 bc = *(const bf16x8*)&cor[(nt*16 + m)*CSTR + k0];
      acc[nt] = MFMA16(aw, bc, acc[nt]);
    }
  }
  const int r0 = (lane >> 4)*4;
  float bo[4];
#pragma unroll
  for (int r = 0; r < 4; ++r) bo[r] = bias[wv*16 + r0 + r];
  float* outb = out + (size_t)pl1g*CHW + h*64;
#pragma unroll
  for (int nt = 0; nt < 4; ++nt)
#pragma unroll
    for (int r = 0; r < 4; ++r){
      const int o = wv*16 + r0 + r;
      outb[o*HW + nt*16 + m] = acc[nt][r] + bo[r];
    }
}

// ======================= R6 TIER (atomics, verified) =======================
__global__ __launch_bounds__(256,4) void k_cor(const short* __restrict__ X,
    short* __restrict__ corg, float* __restrict__ gpartS, float* __restrict__ gpartQ)
{
  __shared__ __align__(16) short tile[32*CSTA];
  const int tid = threadIdx.x, wv = tid >> 6, lane = tid & 63;
  const int bi = blockIdx.x;
  const int pi = bi & 1, h = (bi >> 1) & 63, nn = bi >> 7;
  const int pl1 = (nn/7)*8 + (nn%7);
  const short* f1r  = X + ((size_t)pl1*64 + h)*4096;
  const short* f2pl = X + (size_t)(pl1 + 1)*64*4096;

  {
    int4 z = {0,0,0,0};
    for (int idx = tid; idx < 32*CSTA/8; idx += 256) ((int4*)tile)[idx] = z;
  }
  bf16x8 afr[2][2];
#pragma unroll
  for (int mt = 0; mt < 2; ++mt)
#pragma unroll
    for (int kk = 0; kk < 2; ++kk)
      afr[mt][kk] = load_fragX(f1r, pi, mt, kk, lane);
  __syncthreads();
  const int cI = (lane >> 4)*4;
  const int cJ = lane & 15;
  auto clampr = [&](int r){ return r < 0 ? 0 : (r > 63 ? 63 : r); };
  bf16x8 b[4], nb[4];
  {
    const int row0 = clampr(h + 2*wv - 20);
    const short* f2r = f2pl + row0*4096;
    b[0] = load_fragX(f2r, pi, 0, 0, lane);
    b[1] = load_fragX(f2r, pi, 1, 0, lane);
    b[2] = load_fragX(f2r, pi, 0, 1, lane);
    b[3] = load_fragX(f2r, pi, 1, 1, lane);
  }
  for (int it = 0; it < 6; ++it){
    const int u = it*4 + wv;
    const int row = h + 2*u - 20;
    if (it < 5){
      const int rown = clampr(row + 8);
      const short* f2r = f2pl + rown*4096;
      nb[0] = load_fragX(f2r, pi, 0, 0, lane);
      nb[1] = load_fragX(f2r, pi, 1, 0, lane);
      nb[2] = load_fragX(f2r, pi, 0, 1, lane);
      nb[3] = load_fragX(f2r, pi, 1, 1, lane);
    }
    if (u < 21 && (unsigned)row < 64u){
      f32x4 a00 = {0.f,0.f,0.f,0.f}, a01 = a00, a10 = a00, a11 = a00;
      a00 = MFMA16(afr[0][0], b[0], a00);
      a01 = MFMA16(afr[0][0], b[1], a01);
      a10 = MFMA16(afr[1][0], b[0], a10);
      a11 = MFMA16(afr[1][0], b[1], a11);
      a00 = MFMA16(afr[0][1], b[2], a00);
      a01 = MFMA16(afr[0][1], b[3], a01);
      a10 = MFMA16(afr[1][1], b[2], a10);
      a11 = MFMA16(afr[1][1], b[3], a11);
      const int p21 = u*21;
#define SCAT(v, ii, jj) do{ int q_ = (jj) - (ii) + 10; \
        if ((unsigned)q_ < 21u) tile[(ii)*CSTA + p21 + q_] = f2bf(v); }while(0)
#pragma unroll
      for (int r = 0; r < 4; ++r){
        const int i0 = cI + r;
        SCAT(a00[r], i0,      cJ);
        SCAT(a01[r], i0,      cJ + 16);
        SCAT(a10[r], i0 + 16, cJ);
        SCAT(a11[r], i0 + 16, cJ + 16);
      }
#undef SCAT
    }
#pragma unroll
    for (int j = 0; j < 4; ++j) b[j] = nb[j];
  }
  __syncthreads();
  {
    const int g = tid >> 2, sub = tid & 3;
    if (g < 56){
      float s[8], s2[8];
#pragma unroll
      for (int j = 0; j < 8; ++j){ s[j] = 0.f; s2[j] = 0.f; }
      for (int rr = 0; rr < 8; ++rr){
        const int row = sub*8 + rr;
        bf16x8 v = *(const bf16x8*)&tile[row*CSTA + g*8];
#pragma unroll
        for (int j = 0; j < 8; ++j){
          float f = bf2f(v[j]);
          s[j] += f; s2[j] += f*f;
        }
      }
#pragma unroll
      for (int j = 0; j < 8; ++j){
        s[j]  += __shfl_xor(s[j], 1);  s[j]  += __shfl_xor(s[j], 2);
        s2[j] += __shfl_xor(s2[j], 1); s2[j] += __shfl_xor(s2[j], 2);
      }
      if (sub == 0){
        const int slot = (bi & 31)*KPAD + g*8;
#pragma unroll
        for (int j = 0; j < 8; ++j){
          atomicAdd(&gpartS[slot + j], s[j]);
          atomicAdd(&gpartQ[slot + j], s2[j]);
        }
      }
    }
  }
  short* cblk = corg + (size_t)bi*14336;
  for (int c = tid; c < 1792; c += 256){
    const int row = c/56, cg = c - row*56;
    *(bf16x8*)(cblk + row*KPAD + cg*8) = *(const bf16x8*)&tile[row*CSTA + cg*8];
  }
}

__global__ __launch_bounds__(256) void k_finalizeB(const float* __restrict__ gpartS,
    const float* __restrict__ gpartQ, const float* __restrict__ gamma,
    const float* __restrict__ beta, const float* __restrict__ convw,
    short* __restrict__ wpT, float* __restrict__ bias)
{
  __shared__ float s_scale[NPQ], s_shift[NPQ];
  const int tid = threadIdx.x;
  for (int k = tid; k < NPQ; k += 256){
    float s = 0.f, q = 0.f;
    for (int sl = 0; sl < 32; ++sl){
      s += gpartS[sl*KPAD + k];
      q += gpartQ[sl*KPAD + k];
    }
    float m  = s * (1.f/114688.f);
    float v  = q * (1.f/114688.f) - m*m;
    float iv = rsqrtf(v + 1e-5f);
    float sc = gamma[k] * iv;
    s_scale[k] = sc;
    s_shift[k] = beta[k] - m*sc;
  }
  __syncthreads();
  for (int idx = tid; idx < 64*KPAD; idx += 256){
    int o = idx / KPAD, k = idx - o*KPAD;
    float w = (k < NPQ) ? convw[o*NPQ + k] * s_scale[k] : 0.f;
    wpT[idx] = f2bf(w);
  }
  if (tid < 64){
    float b = 0.f;
    for (int k = 0; k < NPQ; ++k) b += s_shift[k] * convw[tid*NPQ + k];
    bias[tid] = b;
  }
}

// ======================= R4 FALLBACK =======================
__global__ __launch_bounds__(256,2) void k_stats(const short* __restrict__ X,
                                                 float* __restrict__ gsum,
                                                 float* __restrict__ gssq,
                                                 int n0, int plane0)
{
  __shared__ float Gbuf[4*1056];
  __shared__ float s_sum[2][NPQ];
  __shared__ float s_ssq[2][NPQ];
  const int tid = threadIdx.x, wv = tid >> 6, lane = tid & 63;
  const int nn = n0 + (blockIdx.x >> 6), h = blockIdx.x & 63;
  const int pl1 = (nn/7)*8 + (nn%7) - plane0;
  const short* f1r  = X + ((size_t)pl1*64 + h)*4096;
  const short* f2pl = X + (size_t)(pl1 + 1)*64*4096;
  float* Gw = Gbuf + wv*1056;

  for (int i = tid; i < 2*NPQ; i += 256){
    (&s_sum[0][0])[i] = 0.f; (&s_ssq[0][0])[i] = 0.f;
  }
  __syncthreads();

  bf16x8 afr[2][2];
  int cur_pi = -1;
  for (int it = 0; it < 11; ++it){
    const int u = it*4 + wv;
    const bool active = (u < 42);
    const int pi = (u >= 21) ? 1 : 0;
    const int p  = u - pi*21;
    const int row = h + 2*p - 20;
    const bool rv = active && ((unsigned)row < 64u);

    if (active && pi != cur_pi){
#pragma unroll
      for (int mt = 0; mt < 2; ++mt)
#pragma unroll
        for (int kk = 0; kk < 2; ++kk)
          afr[mt][kk] = load_fragX(f1r, pi, mt, kk, lane);
      cur_pi = pi;
    }
    if (rv){
      const short* f2r = f2pl + row*4096;
      f32x4 a00 = {0.f,0.f,0.f,0.f}, a01 = a00, a10 = a00, a11 = a00;
#pragma unroll
      for (int kk = 0; kk < 2; ++kk){
        bf16x8 b0 = load_fragX(f2r, pi, 0, kk, lane);
        bf16x8 b1 = load_fragX(f2r, pi, 1, kk, lane);
        a00 = MFMA16(afr[0][kk], b0, a00);
        a01 = MFMA16(afr[0][kk], b1, a01);
        a10 = MFMA16(afr[1][kk], b0, a10);
        a11 = MFMA16(afr[1][kk], b1, a11);
      }
      const int cI = (lane >> 4)*4;
      const int cJ = lane & 15;
#pragma unroll
      for (int r = 0; r < 4; ++r){
        Gw[(cJ     )*33 + cI + r     ] = a00[r];
        Gw[(cJ + 16)*33 + cI + r     ] = a01[r];
        Gw[(cJ     )*33 + cI + r + 16] = a10[r];
        Gw[(cJ + 16)*33 + cI + r + 16] = a11[r];
      }
    }
    __syncthreads();
    if (rv){
      const int q = lane / 3;
      const int seg = lane - q*3;
      float s = 0.f, s2 = 0.f;
      if (lane < 63){
        const int i0 = seg*11;
        const int i1 = (seg == 2) ? 32 : i0 + 11;
        for (int i = i0; i < i1; ++i){
          const int j = i + q - 10;
          if ((unsigned)j < 32u){
            float v = Gw[j*33 + i];
            s += v; s2 += v*v;
          }
        }
      }
      float sA = __shfl(s,  lane+1), sB = __shfl(s,  lane+2);
      float tA = __shfl(s2, lane+1), tB = __shfl(s2, lane+2);
      if (lane < 63 && seg == 0){
        s_sum[pi][p*21 + q] += s + sA + sB;
        s_ssq[pi][p*21 + q] += s2 + tA + tB;
      }
    }
  }
  __syncthreads();
  for (int i = tid; i < NPQ; i += 256){
    atomicAdd(&gsum[i], s_sum[0][i] + s_sum[1][i]);
    atomicAdd(&gssq[i], s_ssq[0][i] + s_ssq[1][i]);
  }
}

__global__ __launch_bounds__(256) void k_finalizeA(const float* __restrict__ gsum,
    const float* __restrict__ gssq, const float* __restrict__ gamma,
    const float* __restrict__ beta, const float* __restrict__ convw,
    short* __restrict__ wpT, float* __restrict__ bias)
{
  __shared__ float s_scale[NPQ], s_shift[NPQ];
  const int tid = threadIdx.x;
  for (int k = tid; k < NPQ; k += 256){
    float m  = gsum[k] * (1.f/114688.f);
    float v  = gssq[k] * (1.f/114688.f) - m*m;
    float iv = rsqrtf(v + 1e-5f);
    float sc = gamma[k] * iv;
    s_scale[k] = sc;
    s_shift[k] = beta[k] - m*sc;
  }
  __syncthreads();
  for (int idx = tid; idx < 64*KPAD; idx += 256){
    int o = idx / KPAD, k = idx - o*KPAD;
    float w = (k < NPQ) ? convw[o*NPQ + k] * s_scale[k] : 0.f;
    wpT[idx] = f2bf(w);
  }
  if (tid < 64){
    float b = 0.f;
    for (int k = 0; k < NPQ; ++k) b += s_shift[k] * convw[tid*NPQ + k];
    bias[tid] = b;
  }
}

__global__ __launch_bounds__(256,2) void k_main(const short* __restrict__ X,
    const short* __restrict__ wpT, const float* __restrict__ bias,
    float* __restrict__ out, int n0, int plane0)
{
  __shared__ __align__(16) short cor[64*CSTR];
  const int tid = threadIdx.x, wv = tid >> 6, lane = tid & 63;
  const int nn = n0 + (blockIdx.x >> 6), h = blockIdx.x & 63;
  const int pl1g = (nn/7)*8 + (nn%7);
  const int pl1 = pl1g - plane0;
  const short* f1r  = X + ((size_t)pl1*64 + h)*4096;
  const short* f2pl = X + (size_t)(pl1 + 1)*64*4096;

  {
    int4 z = {0,0,0,0};
    for (int idx = tid; idx < 64*CSTR/8; idx += 256) ((int4*)cor)[idx] = z;
  }
  __syncthreads();

  bf16x8 afr[2][2];
  int cur_pi = -1;
  for (int it = 0; it < 11; ++it){
    const int u = it*4 + wv;
    const bool active = (u < 42);
    const int pi = (u >= 21) ? 1 : 0;
    const int p  = u - pi*21;
    const int row = h + 2*p - 20;
    const bool rv = active && ((unsigned)row < 64u);

    if (active && pi != cur_pi){
#pragma unroll
      for (int mt = 0; mt < 2; ++mt)
#pragma unroll
        for (int kk = 0; kk < 2; ++kk)
          afr[mt][kk] = load_fragX(f1r, pi, mt, kk, lane);
      cur_pi = pi;
    }
    if (rv){
      const short* f2r = f2pl + row*4096;
      f32x4 a00 = {0.f,0.f,0.f,0.f}, a01 = a00, a10 = a00, a11 = a00;
#pragma unroll
      for (int kk = 0; kk < 2; ++kk){
        bf16x8 b0 = load_fragX(f2r, pi, 0, kk, lane);
        bf16x8 b1 = load_fragX(f2r, pi, 1, kk, lane);
        a00 = MFMA16(afr[0][kk], b0, a00);
        a01 = MFMA16(afr[0][kk], b1, a01);
        a10 = MFMA16(afr[1][kk], b0, a10);
        a11 = MFMA16(afr[1][kk], b1, a11);
      }
      const int cI = (lane >> 4)*4;
      const int cJ = lane & 15;
      const int p21 = p*21;
#define SCAT(v, ii, jj) do{ int q_ = (jj) - (ii) + 10; \
        if ((unsigned)q_ < 21u) cor[(2*(ii)+pi)*CSTR + p21 + q_] = f2bf(v); }while(0)
#pragma unroll
      for (int r = 0; r < 4; ++r){
        const int i0 = cI + r;
        SCAT(a00[r], i0,      cJ);
        SCAT(a01[r], i0,      cJ + 16);
        SCAT(a10[r], i0 + 16, cJ);
        SCAT(a11[r], i0 + 16, cJ + 16);
      }
#undef SCAT
    }
  }
  __syncthreads();

  const int m = lane & 15, kg = lane >> 4;
  const short* wrow = wpT + (wv*16 + m)*KPAD;
  f32x4 acc[4];
#pragma unroll
  for (int nt = 0; nt < 4; ++nt) acc[nt] = (f32x4){0.f,0.f,0.f,0.f};
  for (int kk = 0; kk < 14; ++kk){
    const int k0 = kk*32 + kg*8;
    bf16x8 aw = *(const bf16x8*)(wrow + k0);
#pragma unroll
    for (int nt = 0; nt < 4; ++nt){
      bf16x8 bc = *(const bf16x8*)&cor[(nt*16 + m)*CSTR + k0];
      acc[nt] = MFMA16(aw, bc, acc[nt]);
    }
  }
  const int r0 = (lane >> 4)*4;
  float bo[4];
#pragma unroll
  for (int r = 0; r < 4; ++r) bo[r] = bias[wv*16 + r0 + r];
  float* outb = out + (size_t)pl1g*CHW + h*64;
#pragma unroll
  for (int nt = 0; nt < 4; ++nt)
#pragma unroll
    for (int r = 0; r < 4; ++r){
      const int o = wv*16 + r0 + r;
      outb[o*HW + nt*16 + m] = acc[nt][r] + bo[r];
    }
}

// ---------------- zero frame T=7 ----------------
__global__ __launch_bounds__(256) void k_zero(float* __restrict__ out){
  const int idx = blockIdx.x*256 + threadIdx.x;
  const int b = idx >> 16, r = idx & 65535;
  float4* p = (float4*)(out + (size_t)(b*8 + 7)*CHW);
  p[r] = make_float4(0.f, 0.f, 0.f, 0.f);
}

extern "C" void kernel_launch(void* const* d_in, const int* in_sizes, int n_in,
                              void* d_out, int out_size, void* d_ws, size_t ws_size,
                              hipStream_t stream)
{
  const float* feats = (const float*)d_in[0];
  const float* gamma = (const float*)d_in[1];
  const float* beta  = (const float*)d_in[2];
  const float* convw = (const float*)d_in[3];
  float* out = (float*)d_out;
  float* wsf = (float*)d_ws;

  k_zero<<<1024, 256, 0, stream>>>(out);

  // ---- Tier P: per-block partials + parallel finalize ----
  {
    float* scalek = wsf;                       // [0,448)
    float* shiftk = wsf + 448;                 // [448,896)
    float* biasB  = wsf + 896;                 // [896,960)
    short* wpTB   = (short*)(wsf + 1024);      // 28672 shorts = 14336 floats: [1024,15360)
    float* partS  = wsf + 15360;               // 3584*448: [15360, 1620992)
    float* partQ  = wsf + 1620992;             // [1620992, 3226624)
    short* Xn     = (short*)(wsf + 3226624);   // 8388608 shorts: [3226624, 7420928)
    short* corg   = (short*)(wsf + 7420928);   // 51380224 shorts: [7420928, 33111040)
    const size_t need_p = (size_t)33111040*4;
    if (ws_size >= need_p){
      k_transpose<<<2048, 256, 0, stream>>>(feats, Xn, 0);
      k_cor2<<<3584, 256, 0, stream>>>(Xn, corg, partS, partQ);
      k_red2<<<56, 256, 0, stream>>>(partS, partQ, gamma, beta, scalek, shiftk);
      k_wfold<<<64, 256, 0, stream>>>(scalek, shiftk, convw, wpTB, biasB);
      k_main2<<<1792, 256, 0, stream>>>(corg, wpTB, biasB, out);
      return;
    }
  }

  // ---- Tier A: R6 atomic path (verified) ----
  {
    float* gpartS = wsf;                       // [0, 14336)
    float* gpartQ = wsf + 14336;               // [14336, 28672)
    float* biasB  = wsf + 28672;
    short* wpTB   = (short*)(wsf + 28736);     // [28736, 43072)
    short* Xn     = (short*)(wsf + 43072);
    short* corg   = (short*)(wsf + 4237376);
    const size_t need_a = (size_t)4237376*4 + (size_t)3584*14336*2;
    if (ws_size >= need_a){
      hipMemsetAsync(gpartS, 0, 2*14336*sizeof(float), stream);
      k_transpose<<<2048, 256, 0, stream>>>(feats, Xn, 0);
      k_cor<<<3584, 256, 0, stream>>>(Xn, corg, gpartS, gpartQ);
      k_finalizeB<<<1, 256, 0, stream>>>(gpartS, gpartQ, gamma, beta, convw, wpTB, biasB);
      k_main2<<<1792, 256, 0, stream>>>(corg, wpTB, biasB, out);
      return;
    }
  }

  // ---- R4 fallback ----
  float* gsum = wsf;
  float* gssq = wsf + 441;
  float* bias = wsf + 896;
  short* wpT  = (short*)(wsf + 1024);
  short* X    = (short*)(wsf + 16384);
  const size_t fixedB = 16384*sizeof(float);
  const size_t planeB = (size_t)CHW*2;

  hipMemsetAsync(gsum, 0, 882*sizeof(float), stream);
  if (ws_size >= fixedB + 32*planeB){
    k_transpose<<<2048, 256, 0, stream>>>(feats, X, 0);
    k_stats<<<1792, 256, 0, stream>>>(X, gsum, gssq, 0, 0);
    k_finalizeA<<<1, 256, 0, stream>>>(gsum, gssq, gamma, beta, convw, wpT, bias);
    k_main<<<1792, 256, 0, stream>>>(X, wpT, bias, out, 0, 0);
  } else if (ws_size >= fixedB + 8*planeB){
    for (int b = 0; b < 4; ++b){
      k_transpose<<<512, 256, 0, stream>>>(feats, X, b*8);
      k_stats<<<448, 256, 0, stream>>>(X, gsum, gssq, b*7, b*8);
    }
    k_finalizeA<<<1, 256, 0, stream>>>(gsum, gssq, gamma, beta, convw, wpT, bias);
    for (int b = 0; b < 4; ++b){
      k_transpose<<<512, 256, 0, stream>>>(feats, X, b*8);
      k_main<<<448, 256, 0, stream>>>(X, wpT, bias, out, b*7, b*8);
    }
  } else {
    for (int n = 0; n < 28; ++n){
      const int pl = (n/7)*8 + (n%7);
      k_transpose<<<128, 256, 0, stream>>>(feats, X, pl);
      k_stats<<<64, 256, 0, stream>>>(X, gsum, gssq, n, pl);
    }
    k_finalizeA<<<1, 256, 0, stream>>>(gsum, gssq, gamma, beta, convw, wpT, bias);
    for (int n = 0; n < 28; ++n){
      const int pl = (n/7)*8 + (n%7);
      k_transpose<<<128, 256, 0, stream>>>(feats, X, pl);
      k_main<<<64, 256, 0, stream>>>(X, wpT, bias, out, n, pl);
    }
  }
}